// Round 6
// baseline (165.046 us; speedup 1.0000x reference)
//
#include <hip/hip_runtime.h>
#include <math.h>
#include <float.h>

#define B_SZ 512
#define C_SZ 1000
#define D_SZ 512
#define K_TOP 10
#define K2 1024                       // [x^2 | x] vs [rd | -2*rd*p]
#define NSPLIT 4
#define KSPLIT 256
#define BC (B_SZ * C_SZ)

// ws layout:
//   halves: Whi [1024][1024], Wlo [1024][1024]   (4 MB)
//   floats from 1048576: flagB[256 pad], flagP[512+pad], t3[1024], part[4][B][C]
#define WHI_OFFH 0
#define WLO_OFFH (1024 * 1024)
#define FLAGB_OFF 1048576
#define FLAGP_OFF (FLAGB_OFF + 256)
#define T3_OFF    (FLAGB_OFF + 1024)
#define PART_OFF  (T3_OFF + 1024)
#define MAGIC 0x5F3C0DE5u

#define BM 64
#define BN 64
#define BK 32
#define LDA 40     // A tile stride (f16): b128 frag reads conflict-free (R1-proven)
#define LDB 264    // B slice stride (f16): 2-way bank alias only (free, m136)

using f16x8 = __attribute__((ext_vector_type(8))) _Float16;
using f32x4 = __attribute__((ext_vector_type(4))) float;

#if __has_builtin(__builtin_amdgcn_exp2f)
#define FAST_EXP2(x) __builtin_amdgcn_exp2f(x)
#else
#define FAST_EXP2(x) exp2f(x)
#endif
#if __has_builtin(__builtin_amdgcn_sqrtf)
#define FAST_SQRT(x) __builtin_amdgcn_sqrtf(x)
#else
#define FAST_SQRT(x) sqrtf(x)
#endif
#define LOG2E 1.44269504088896340736f

__device__ __forceinline__ void split2(float v, _Float16& h, _Float16& l) {
    h = (_Float16)v;
    l = (_Float16)(v - (float)h);
}

// ---------------------------------------------------------------------------
// Single-dispatch fused kernel. Grid (16,8,4) = 512 blocks = exact 2/CU
// co-residency (spin-safe). Producer/consumer via agent-scope flags (G16).
// Stage 0: kz==0 blocks compute 8 class rows each (1024 total, NO redundancy
//   -- R5's 32x redundant reads were 201 MB of L3 traffic ~26 us), write W
//   hi/lo f16 + t3 to ws, release flagB.
// Stage 1/2: all blocks wait their cx's 8 flagB, acquire, load B-slice to LDS.
// Stage 3: R1-verified split-f16 MFMA GEMM -> part[kz].
// Stage 4/5: release flagP; kz==3 blocks wait their by-group's 64 flagP and
//   run the verified topk body in-kernel (deletes the topk dispatch+boundary).
// ---------------------------------------------------------------------------
__global__ __launch_bounds__(256, 2) void fused_all(const float* __restrict__ x,
                                                    const float* __restrict__ protos,
                                                    const float* __restrict__ ex2,
                                                    const float* __restrict__ ex1,
                                                    const int* __restrict__ cls_num,
                                                    const int* __restrict__ proto_label,
                                                    float* __restrict__ ws,
                                                    float* __restrict__ out) {
    __shared__ __align__(16) _Float16 Ah[BM][LDA];
    __shared__ __align__(16) _Float16 Al[BM][LDA];
    __shared__ __align__(16) _Float16 BSh[BN][LDB];
    __shared__ __align__(16) _Float16 BSl[BN][LDB];

    _Float16* Whi = (_Float16*)ws + WHI_OFFH;
    _Float16* Wlo = (_Float16*)ws + WLO_OFFH;
    unsigned int* flagB = (unsigned int*)(ws + FLAGB_OFF);
    unsigned int* flagP = (unsigned int*)(ws + FLAGP_OFF);
    float* t3   = ws + T3_OFF;
    float* part = ws + PART_OFF;

    const int tid  = threadIdx.x;
    const int lane = tid & 63;
    const int w    = tid >> 6;
    const int cx = blockIdx.x, by = blockIdx.y, kz = blockIdx.z;
    const int c0 = cx * BN;
    const int b0 = by * BM;
    const bool isRd = (kz < 2);

    // ---- Stage 0: producers (kz==0) compute rows c0+by*8 .. +8 ------------
    if (kz == 0) {
        #pragma unroll
        for (int r = 0; r < 2; r++) {
            const int c = c0 + by * 8 + w * 2 + r;
            if (c < C_SZ) {
                const size_t rb = (size_t)c * D_SZ + lane * 8;
                float e2v[8], e1v[8], pv[8];
                *(float4*)&e2v[0] = *(const float4*)(ex2 + rb);
                *(float4*)&e2v[4] = *(const float4*)(ex2 + rb + 4);
                *(float4*)&e1v[0] = *(const float4*)(ex1 + rb);
                *(float4*)&e1v[4] = *(const float4*)(ex1 + rb + 4);
                *(float4*)&pv[0]  = *(const float4*)(protos + rb);
                *(float4*)&pv[4]  = *(const float4*)(protos + rb + 4);
                const float N = (float)cls_num[c];

                float v[8], mn = FLT_MAX;
                #pragma unroll
                for (int k = 0; k < 8; k++) {
                    v[k] = FAST_SQRT(N * e2v[k] * e2v[k] - e1v[k] * e1v[k]);
                    mn = fminf(mn, v[k]);
                }
                #pragma unroll
                for (int off = 1; off < 64; off <<= 1) mn = fminf(mn, __shfl_xor(mn, off));

                float ev[8], s = 0.f, te = 0.f;
                #pragma unroll
                for (int k = 0; k < 8; k++) {
                    ev[k] = FAST_EXP2((mn - v[k]) * LOG2E);
                    s += ev[k];
                    te = fmaf(ev[k] * pv[k], pv[k], te);
                }
                #pragma unroll
                for (int off = 1; off < 64; off <<= 1) {
                    s  += __shfl_xor(s, off);
                    te += __shfl_xor(te, off);
                }
                const float inv = 1.0f / s;
                if (lane == 0) t3[c] = te * inv;

                f16x8 h1, l1, h2, l2;
                #pragma unroll
                for (int k = 0; k < 8; k++) {
                    const float rdv = ev[k] * inv;
                    const float w2  = -2.0f * rdv * pv[k];
                    _Float16 hh, ll;
                    split2(rdv, hh, ll); h1[k] = hh; l1[k] = ll;
                    split2(w2,  hh, ll); h2[k] = hh; l2[k] = ll;
                }
                _Float16* wh = Whi + (size_t)c * K2 + lane * 8;
                _Float16* wl = Wlo + (size_t)c * K2 + lane * 8;
                *(f16x8*)(wh)         = h1;
                *(f16x8*)(wh + D_SZ)  = h2;
                *(f16x8*)(wl)         = l1;
                *(f16x8*)(wl + D_SZ)  = l2;
            }
        }
        __syncthreads();                    // all waves' W stores drained (vmcnt)
        if (tid == 0) {
            __threadfence();                // device release: writeback L2 (cross-XCD)
            __hip_atomic_store(&flagB[cx * 8 + by], MAGIC,
                               __ATOMIC_RELEASE, __HIP_MEMORY_SCOPE_AGENT);
        }
    }

    // ---- Stage 1: wait for my cx's 8 producer groups -----------------------
    if (w == 0 && lane < 8) {
        for (int it = 0; it < (1 << 22); ++it) {   // bounded: bug -> fail, not hang
            if (__hip_atomic_load(&flagB[cx * 8 + lane], __ATOMIC_RELAXED,
                                  __HIP_MEMORY_SCOPE_AGENT) == MAGIC) break;
            __builtin_amdgcn_s_sleep(4);
        }
    }
    __syncthreads();
    __threadfence();                        // device acquire: invalidate stale L2

    // ---- Stage 2: load my B-slice (64 rows x 256 cols, hi/lo) into LDS ----
    const int srow = tid >> 2;              // 0..63
    const int cseg = (tid & 3) * 8;         // 0,8,16,24
    {
        const int c = c0 + srow;
        #pragma unroll
        for (int p = 0; p < 8; p++) {
            const int col = cseg + p * 32;  // 0..255
            f16x8 hh, ll;
            if (c < C_SZ) {
                hh = *(const f16x8*)(Whi + (size_t)c * K2 + kz * KSPLIT + col);
                ll = *(const f16x8*)(Wlo + (size_t)c * K2 + kz * KSPLIT + col);
            } else {
                #pragma unroll
                for (int k = 0; k < 8; k++) { hh[k] = (_Float16)0.f; ll[k] = (_Float16)0.f; }
            }
            *(f16x8*)&BSh[srow][col] = hh;
            *(f16x8*)&BSl[srow][col] = ll;
        }
    }
    __syncthreads();                        // B slice visible

    // ---- Stage 3: GEMM (R1-verified structure) -----------------------------
    const int khalf0 = isRd ? kz * KSPLIT : kz * KSPLIT - D_SZ;
    const int sseg = (tid & 3) * 8;
    const int mw = (w >> 1) * 32;
    const int nw = (w & 1) * 32;
    const int lr = lane & 15;
    const int kg = lane >> 4;

    f32x4 acc[2][2];
    #pragma unroll
    for (int i = 0; i < 2; i++)
        #pragma unroll
        for (int j = 0; j < 2; j++)
            #pragma unroll
            for (int r = 0; r < 4; r++) acc[i][j][r] = 0.f;

    for (int ch = 0; ch < KSPLIT / BK; ch++) {
        const int kx = khalf0 + ch * BK + sseg;

        float4 a0 = *(const float4*)(x + (size_t)(b0 + srow) * D_SZ + kx);
        float4 a1 = *(const float4*)(x + (size_t)(b0 + srow) * D_SZ + kx + 4);
        if (isRd) {
            a0.x *= a0.x; a0.y *= a0.y; a0.z *= a0.z; a0.w *= a0.w;
            a1.x *= a1.x; a1.y *= a1.y; a1.z *= a1.z; a1.w *= a1.w;
        }
        const float av[8] = {a0.x, a0.y, a0.z, a0.w, a1.x, a1.y, a1.z, a1.w};
        f16x8 ah, al;
        #pragma unroll
        for (int j = 0; j < 8; j++) {
            _Float16 hh, ll;
            split2(av[j], hh, ll);
            ah[j] = hh; al[j] = ll;
        }

        __syncthreads();                    // previous iter's A-frag reads done
        *(f16x8*)&Ah[srow][sseg] = ah;
        *(f16x8*)&Al[srow][sseg] = al;
        __syncthreads();                    // A tile visible

        f16x8 fah[2], fal[2], fbh[2], fbl[2];
        #pragma unroll
        for (int i = 0; i < 2; i++) {
            fah[i] = *(const f16x8*)&Ah[mw + i * 16 + lr][kg * 8];
            fal[i] = *(const f16x8*)&Al[mw + i * 16 + lr][kg * 8];
            fbh[i] = *(const f16x8*)&BSh[nw + i * 16 + lr][ch * BK + kg * 8];
            fbl[i] = *(const f16x8*)&BSl[nw + i * 16 + lr][ch * BK + kg * 8];
        }
        #pragma unroll
        for (int i = 0; i < 2; i++)
            #pragma unroll
            for (int j = 0; j < 2; j++) {
                acc[i][j] = __builtin_amdgcn_mfma_f32_16x16x32_f16(fal[i], fbl[j], acc[i][j], 0, 0, 0);
                acc[i][j] = __builtin_amdgcn_mfma_f32_16x16x32_f16(fah[i], fbl[j], acc[i][j], 0, 0, 0);
                acc[i][j] = __builtin_amdgcn_mfma_f32_16x16x32_f16(fal[i], fbh[j], acc[i][j], 0, 0, 0);
                acc[i][j] = __builtin_amdgcn_mfma_f32_16x16x32_f16(fah[i], fbh[j], acc[i][j], 0, 0, 0);
            }
    }

    // C/D layout (verified m89/m91): col = lane&15, row = (lane>>4)*4 + reg
    float* o = part + (size_t)kz * BC;
    #pragma unroll
    for (int i = 0; i < 2; i++) {
        #pragma unroll
        for (int j = 0; j < 2; j++) {
            const int c = c0 + nw + j * 16 + lr;
            if (c < C_SZ) {
                #pragma unroll
                for (int r = 0; r < 4; r++) {
                    const int b = b0 + mw + i * 16 + kg * 4 + r;
                    o[(size_t)b * C_SZ + c] = acc[i][j][r];
                }
            }
        }
    }

    // ---- Stage 4: publish my part tile -------------------------------------
    __syncthreads();                        // all part stores drained
    if (tid == 0) {
        __threadfence();
        __hip_atomic_store(&flagP[by * 64 + cx * 4 + kz], MAGIC,
                           __ATOMIC_RELEASE, __HIP_MEMORY_SCOPE_AGENT);
    }

    // ---- Stage 5: topk role (kz==3): rows (by*16+cx)*4 .. +4 --------------
    if (kz == 3) {
        if (w == 0) {                       // wait all 64 part tiles of my by
            for (int it = 0; it < (1 << 22); ++it) {
                if (__hip_atomic_load(&flagP[by * 64 + lane], __ATOMIC_RELAXED,
                                      __HIP_MEMORY_SCOPE_AGENT) == MAGIC) break;
                __builtin_amdgcn_s_sleep(8);
            }
        }
        __syncthreads();
        __threadfence();                    // acquire before reading part

        const int b = (by * 16 + cx) * 4 + w;

        float vals[16];
        #pragma unroll
        for (int j = 0; j < 16; j++) {
            const int c = lane + j * 64;
            if (c < C_SZ) {
                const size_t idx = (size_t)b * C_SZ + c;
                float s = t3[c];
                #pragma unroll
                for (int z = 0; z < NSPLIT; z++)
                    s += part[(size_t)z * BC + idx];
                vals[j] = s;
            } else {
                vals[j] = FLT_MAX;
            }
        }

        float kv[K_TOP];
        int ki[K_TOP];
        for (int t = 0; t < K_TOP; t++) {
            float bv = FLT_MAX;
            int bi = 0x7fffffff;
            #pragma unroll
            for (int j = 0; j < 16; j++) {
                const int c = lane + j * 64;
                if (vals[j] < bv) { bv = vals[j]; bi = c; }
            }
            #pragma unroll
            for (int off = 1; off < 64; off <<= 1) {
                const float ov = __shfl_xor(bv, off);
                const int oi = __shfl_xor(bi, off);
                if (ov < bv || (ov == bv && oi < bi)) { bv = ov; bi = oi; }
            }
            kv[t] = bv;
            ki[t] = bi;
            if ((bi & 63) == lane) vals[bi >> 6] = FLT_MAX;
        }

        if (lane == 0) {
            float S = 0.f;
            #pragma unroll
            for (int t = 0; t < K_TOP; t++) S += kv[t];
            float conf[K_TOP];
            #pragma unroll
            for (int t = 0; t < K_TOP; t++) {
                conf[t] = S / kv[t];
                out[B_SZ + b * K_TOP + t] = conf[t];
            }
            int best = 0;
            for (int t = 1; t < K_TOP; t++)
                if (conf[t] > conf[best]) best = t;
            out[b] = (float)proto_label[ki[best]];
        }
    }
}

extern "C" void kernel_launch(void* const* d_in, const int* in_sizes, int n_in,
                              void* d_out, int out_size, void* d_ws, size_t ws_size,
                              hipStream_t stream) {
    const float* x           = (const float*)d_in[0];
    const float* protos      = (const float*)d_in[1];
    const float* ex2         = (const float*)d_in[2];
    const float* ex1         = (const float*)d_in[3];
    const int*   cls_num     = (const int*)d_in[4];
    const int*   proto_label = (const int*)d_in[5];

    float* ws  = (float*)d_ws;
    float* out = (float*)d_out;

    dim3 g((C_SZ + BN - 1) / BN, B_SZ / BM, NSPLIT);   // 16 x 8 x 4 = 512
    fused_all<<<g, 256, 0, stream>>>(x, protos, ex2, ex1, cls_num, proto_label, ws, out);
}

// Round 7
// 104.352 us; speedup vs baseline: 1.5816x; 1.5816x over previous
//
#include <hip/hip_runtime.h>
#include <math.h>
#include <float.h>

#define B_SZ 512
#define C_SZ 1000
#define D_SZ 512
#define K_TOP 10
#define K2 1024                       // [x^2 | x] vs [rd | -2*rd*p]

// ws layout (floats): simi [B][C] only (2.05 MB)
#define SIMI_OFF 0

// Split-C fused GEMM: each block owns 128 b-rows x 16 classes, FULL K=1024.
// No split-K partials -> no cross-block reduction -> no 3rd dispatch and no
// sync (R2/R6 measured intra-kernel cross-block sync at 70-90 us: dead).
#define BM 128
#define BN 16
#define BK 32
#define LDA 40      // A tile stride (f16): 80B rows, 2-way bank alias (free)
#define LDB 1032    // B row stride (f16): 2064B = 516 dw == 4 mod 32 -> 2-way

using f16x8 = __attribute__((ext_vector_type(8))) _Float16;
using f32x4 = __attribute__((ext_vector_type(4))) float;

#if __has_builtin(__builtin_amdgcn_exp2f)
#define FAST_EXP2(x) __builtin_amdgcn_exp2f(x)
#else
#define FAST_EXP2(x) exp2f(x)
#endif
#if __has_builtin(__builtin_amdgcn_sqrtf)
#define FAST_SQRT(x) __builtin_amdgcn_sqrtf(x)
#else
#define FAST_SQRT(x) sqrtf(x)
#endif
#define LOG2E 1.44269504088896340736f

__device__ __forceinline__ void split2(float v, _Float16& h, _Float16& l) {
    h = (_Float16)v;
    l = (_Float16)(v - (float)h);
}

// ---------------------------------------------------------------------------
// Fused prep+GEMM, split-C. Grid 256 blocks (cx = bid&63 -> same-cx blocks on
// same XCD under %8 round-robin => prep input re-reads are L2-local), 512 thr
// (8 waves), 1 block/CU (86.6 KB LDS).
// Phase A: 16 classes/block (2 per wave, 4x redundancy total): full-row
//   softmax with HW transcendentals; write [rd | -2*rd*p] hi/lo f16 into
//   persistent LDS B tile; t3 into LDS (epilogue folds it into simi).
// Phase B: full-K split-f16 MFMA GEMM (R1-verified fragment & C/D layout,
//   BN=16 degenerate case), epilogue simi[b][c] = acc + t3[c].
// ---------------------------------------------------------------------------
__global__ __launch_bounds__(512, 2) void fused_kernel(const float* __restrict__ x,
                                                       const float* __restrict__ protos,
                                                       const float* __restrict__ ex2,
                                                       const float* __restrict__ ex1,
                                                       const int* __restrict__ cls_num,
                                                       float* __restrict__ simi) {
    __shared__ __align__(16) _Float16 Ah[BM][LDA];
    __shared__ __align__(16) _Float16 Al[BM][LDA];
    __shared__ __align__(16) _Float16 BSh[BN][LDB];
    __shared__ __align__(16) _Float16 BSl[BN][LDB];
    __shared__ float t3s[BN];

    const int tid  = threadIdx.x;
    const int lane = tid & 63;
    const int w    = tid >> 6;            // 0..7
    const int cx = blockIdx.x & 63;       // low bits -> XCD-local class groups
    const int by = blockIdx.x >> 6;       // 0..3
    const int c0 = cx * BN;
    const int b0 = by * BM;
    if (c0 >= C_SZ) return;               // cx==63 (c0=1008): idle block

    // ---- Phase A: 2 class rows per wave ------------------------------------
    #pragma unroll
    for (int r = 0; r < 2; r++) {
        const int lc = w * 2 + r;         // 0..15
        const int c  = c0 + lc;
        if (c < C_SZ) {
            const size_t rb = (size_t)c * D_SZ + lane * 8;
            float e2v[8], e1v[8], pv[8];
            *(float4*)&e2v[0] = *(const float4*)(ex2 + rb);
            *(float4*)&e2v[4] = *(const float4*)(ex2 + rb + 4);
            *(float4*)&e1v[0] = *(const float4*)(ex1 + rb);
            *(float4*)&e1v[4] = *(const float4*)(ex1 + rb + 4);
            *(float4*)&pv[0]  = *(const float4*)(protos + rb);
            *(float4*)&pv[4]  = *(const float4*)(protos + rb + 4);
            const float N = (float)cls_num[c];

            float v[8], mn = FLT_MAX;
            #pragma unroll
            for (int k = 0; k < 8; k++) {
                v[k] = FAST_SQRT(N * e2v[k] * e2v[k] - e1v[k] * e1v[k]);
                mn = fminf(mn, v[k]);
            }
            #pragma unroll
            for (int off = 1; off < 64; off <<= 1) mn = fminf(mn, __shfl_xor(mn, off));

            float ev[8], s = 0.f, te = 0.f;
            #pragma unroll
            for (int k = 0; k < 8; k++) {
                ev[k] = FAST_EXP2((mn - v[k]) * LOG2E);
                s += ev[k];
                te = fmaf(ev[k] * pv[k], pv[k], te);
            }
            #pragma unroll
            for (int off = 1; off < 64; off <<= 1) {
                s  += __shfl_xor(s, off);
                te += __shfl_xor(te, off);
            }
            const float inv = 1.0f / s;
            if (lane == 0) t3s[lc] = te * inv;

            f16x8 h1, l1, h2, l2;
            #pragma unroll
            for (int k = 0; k < 8; k++) {
                const float rdv = ev[k] * inv;
                const float w2  = -2.0f * rdv * pv[k];
                _Float16 hh, ll;
                split2(rdv, hh, ll); h1[k] = hh; l1[k] = ll;
                split2(w2,  hh, ll); h2[k] = hh; l2[k] = ll;
            }
            const int d = lane * 8;       // feature base 0..504
            *(f16x8*)&BSh[lc][d]         = h1;
            *(f16x8*)&BSh[lc][D_SZ + d]  = h2;
            *(f16x8*)&BSl[lc][d]         = l1;
            *(f16x8*)&BSl[lc][D_SZ + d]  = l2;
        } else {
            // pad class: zero the B row so MFMA contributions vanish
            f16x8 z;
            #pragma unroll
            for (int k = 0; k < 8; k++) z[k] = (_Float16)0.f;
            const int d = lane * 8;
            *(f16x8*)&BSh[lc][d]        = z;
            *(f16x8*)&BSh[lc][D_SZ + d] = z;
            *(f16x8*)&BSl[lc][d]        = z;
            *(f16x8*)&BSl[lc][D_SZ + d] = z;
        }
    }
    __syncthreads();                      // B tile + t3s complete

    // ---- Phase B: full-K GEMM (R1-verified fragment/C-D layout) ------------
    const int srow = tid >> 2;            // 0..127 staging row
    const int sseg = (tid & 3) * 8;       // 0,8,16,24
    const int mw = w * 16;                // wave tile origin in b (0..112)
    const int lr = lane & 15;
    const int kg = lane >> 4;

    f32x4 acc;
    #pragma unroll
    for (int r = 0; r < 4; r++) acc[r] = 0.f;

    for (int ch = 0; ch < K2 / BK; ch++) {        // 32 chunks
        const bool sq = (ch < 16);                // first half of K2 -> x^2
        const int kx = (sq ? ch * BK : ch * BK - D_SZ) + sseg;

        float4 a0 = *(const float4*)(x + (size_t)(b0 + srow) * D_SZ + kx);
        float4 a1 = *(const float4*)(x + (size_t)(b0 + srow) * D_SZ + kx + 4);
        if (sq) {
            a0.x *= a0.x; a0.y *= a0.y; a0.z *= a0.z; a0.w *= a0.w;
            a1.x *= a1.x; a1.y *= a1.y; a1.z *= a1.z; a1.w *= a1.w;
        }
        const float av[8] = {a0.x, a0.y, a0.z, a0.w, a1.x, a1.y, a1.z, a1.w};
        f16x8 ah, al;
        #pragma unroll
        for (int j = 0; j < 8; j++) {
            _Float16 hh, ll;
            split2(av[j], hh, ll);
            ah[j] = hh; al[j] = ll;
        }

        __syncthreads();                  // previous iter's A-frag reads done
        *(f16x8*)&Ah[srow][sseg] = ah;
        *(f16x8*)&Al[srow][sseg] = al;
        __syncthreads();                  // A tile visible

        const f16x8 fah = *(const f16x8*)&Ah[mw + lr][kg * 8];
        const f16x8 fal = *(const f16x8*)&Al[mw + lr][kg * 8];
        const f16x8 fbh = *(const f16x8*)&BSh[lr][ch * BK + kg * 8];
        const f16x8 fbl = *(const f16x8*)&BSl[lr][ch * BK + kg * 8];

        acc = __builtin_amdgcn_mfma_f32_16x16x32_f16(fal, fbl, acc, 0, 0, 0);
        acc = __builtin_amdgcn_mfma_f32_16x16x32_f16(fah, fbl, acc, 0, 0, 0);
        acc = __builtin_amdgcn_mfma_f32_16x16x32_f16(fal, fbh, acc, 0, 0, 0);
        acc = __builtin_amdgcn_mfma_f32_16x16x32_f16(fah, fbh, acc, 0, 0, 0);
    }

    // Epilogue: C/D layout (verified m89/m91): col = lane&15, row = kg*4+reg.
    // simi = acc + t3[c] (t3 folded here so topk needs neither part nor t3).
    const int c = c0 + lr;
    if (c < C_SZ) {
        const float t3v = t3s[lr];
        #pragma unroll
        for (int r = 0; r < 4; r++) {
            const int b = b0 + mw + kg * 4 + r;
            simi[(size_t)b * C_SZ + c] = acc[r] + t3v;
        }
    }
}

// ---------------------------------------------------------------------------
// Top-K: per row (one wave each), 10x butterfly min with index tie-break
// (lower index wins == lax.top_k stability). Reads simi directly.
// out[0..B): predict (float-encoded int), out[B..): topk_conf [B][K]
// ---------------------------------------------------------------------------
__global__ __launch_bounds__(256) void topk_kernel(const float* __restrict__ ws,
                                                   const int* __restrict__ proto_label,
                                                   float* __restrict__ out) {
    const float* simi = ws + SIMI_OFF;
    const int wid = threadIdx.x >> 6;
    const int lane = threadIdx.x & 63;
    const int b = blockIdx.x * 4 + wid;

    float vals[16];
    #pragma unroll
    for (int j = 0; j < 16; j++) {
        const int c = lane + j * 64;
        vals[j] = (c < C_SZ) ? simi[(size_t)b * C_SZ + c] : FLT_MAX;
    }

    float kv[K_TOP];
    int ki[K_TOP];
    for (int t = 0; t < K_TOP; t++) {
        float bv = FLT_MAX;
        int bi = 0x7fffffff;
        #pragma unroll
        for (int j = 0; j < 16; j++) {
            const int c = lane + j * 64;
            if (vals[j] < bv) { bv = vals[j]; bi = c; }
        }
        #pragma unroll
        for (int off = 1; off < 64; off <<= 1) {
            const float ov = __shfl_xor(bv, off);
            const int oi = __shfl_xor(bi, off);
            if (ov < bv || (ov == bv && oi < bi)) { bv = ov; bi = oi; }
        }
        kv[t] = bv;
        ki[t] = bi;
        if ((bi & 63) == lane) vals[bi >> 6] = FLT_MAX;
    }

    if (lane == 0) {
        float S = 0.f;
        #pragma unroll
        for (int t = 0; t < K_TOP; t++) S += kv[t];
        float conf[K_TOP];
        #pragma unroll
        for (int t = 0; t < K_TOP; t++) {
            conf[t] = S / kv[t];
            out[B_SZ + b * K_TOP + t] = conf[t];
        }
        int best = 0;
        for (int t = 1; t < K_TOP; t++)
            if (conf[t] > conf[best]) best = t;
        out[b] = (float)proto_label[ki[best]];
    }
}

extern "C" void kernel_launch(void* const* d_in, const int* in_sizes, int n_in,
                              void* d_out, int out_size, void* d_ws, size_t ws_size,
                              hipStream_t stream) {
    const float* x           = (const float*)d_in[0];
    const float* protos      = (const float*)d_in[1];
    const float* ex2         = (const float*)d_in[2];
    const float* ex1         = (const float*)d_in[3];
    const int*   cls_num     = (const int*)d_in[4];
    const int*   proto_label = (const int*)d_in[5];

    float* ws  = (float*)d_ws;
    float* out = (float*)d_out;

    fused_kernel<<<256, 512, 0, stream>>>(x, protos, ex2, ex1, cls_num,
                                          ws + SIMI_OFF);

    topk_kernel<<<B_SZ / 4, 256, 0, stream>>>(ws, proto_label, out);
}

// Round 9
// 96.589 us; speedup vs baseline: 1.7087x; 1.0804x over previous
//
#include <hip/hip_runtime.h>
#include <math.h>
#include <float.h>

#define B_SZ 512
#define C_SZ 1000
#define D_SZ 512
#define K_TOP 10
#define K2 1024                       // [x^2 | x] vs [rd | -2*rd*p]

// ws layout (floats): simi [B][C] only (2.05 MB)
#define SIMI_OFF 0

// Split-C fused GEMM: each block owns 128 b-rows x 16 classes, FULL K=1024.
// R7 lesson: 32 barrier-locked chunks at 1 block/CU exposed full load latency
// (~31 us). Fix: BK=64 (16 chunks) + register prefetch of chunk ch+1 issued
// before ch's barriers, chunk-0 loads issued before Phase A.
#define BM 128
#define BN 16
#define BK 64
#define LDA 72      // A tile stride (f16): 144B rows -> 2-way bank alias (free)
#define LDB 1032    // B row stride (f16): 2064B rows -> 2-way alias (free)

using f16x8 = __attribute__((ext_vector_type(8))) _Float16;
using f32x4 = __attribute__((ext_vector_type(4))) float;

#if __has_builtin(__builtin_amdgcn_exp2f)
#define FAST_EXP2(x) __builtin_amdgcn_exp2f(x)
#else
#define FAST_EXP2(x) exp2f(x)
#endif
#if __has_builtin(__builtin_amdgcn_sqrtf)
#define FAST_SQRT(x) __builtin_amdgcn_sqrtf(x)
#else
#define FAST_SQRT(x) sqrtf(x)
#endif
#define LOG2E 1.44269504088896340736f

__device__ __forceinline__ void split2(float v, _Float16& h, _Float16& l) {
    h = (_Float16)v;
    l = (_Float16)(v - (float)h);
}

// ---------------------------------------------------------------------------
// Fused prep+GEMM, split-C. Grid 256 blocks (cx = bid&63 -> same-cx class
// groups L2-local under %8 XCD round-robin), 512 thr (8 waves), 1 block/CU
// (100.6 KB LDS).
// Phase A: 16 classes/block (2/wave, 4x total redundancy): full-row softmax
//   with HW transcendentals -> [rd | -2*rd*p] hi/lo f16 in persistent LDS;
//   t3 in LDS (folded into simi at epilogue).
// Phase B: full-K split-f16 MFMA GEMM (R1-verified fragment & C/D layout),
//   BK=64, register-double-buffered staging. simi[b][c] = acc + t3[c].
// ---------------------------------------------------------------------------
__global__ __launch_bounds__(512, 1) void fused_kernel(const float* __restrict__ x,
                                                       const float* __restrict__ protos,
                                                       const float* __restrict__ ex2,
                                                       const float* __restrict__ ex1,
                                                       const int* __restrict__ cls_num,
                                                       float* __restrict__ simi) {
    __shared__ __align__(16) _Float16 Ah[BM][LDA];
    __shared__ __align__(16) _Float16 Al[BM][LDA];
    __shared__ __align__(16) _Float16 BSh[BN][LDB];
    __shared__ __align__(16) _Float16 BSl[BN][LDB];
    __shared__ float t3s[BN];

    const int tid  = threadIdx.x;
    const int lane = tid & 63;
    const int w    = tid >> 6;            // 0..7
    const int cx = blockIdx.x & 63;       // low bits -> XCD-local class groups
    const int by = blockIdx.x >> 6;       // 0..3
    const int c0 = cx * BN;
    const int b0 = by * BM;
    if (c0 >= C_SZ) return;               // cx==63 (c0=1008): idle block

    // staging coords (Phase B), needed for the early prologue load
    const int srow = tid >> 2;            // 0..127
    const int scol = (tid & 3) * 16;      // k-offset within 64-wide chunk

    auto load_chunk = [&](int ch, float4* dst) {
        const int kx = (ch < 8 ? ch * BK : ch * BK - D_SZ) + scol;
        const float* xp = x + (size_t)(b0 + srow) * D_SZ + kx;
        dst[0] = *(const float4*)(xp);
        dst[1] = *(const float4*)(xp + 4);
        dst[2] = *(const float4*)(xp + 8);
        dst[3] = *(const float4*)(xp + 12);
    };

    float4 cur[4], nxt[4];
    load_chunk(0, cur);                   // in flight during all of Phase A

    // ---- Phase A: 2 class rows per wave ------------------------------------
    #pragma unroll
    for (int r = 0; r < 2; r++) {
        const int lc = w * 2 + r;         // 0..15
        const int c  = c0 + lc;
        if (c < C_SZ) {
            const size_t rb = (size_t)c * D_SZ + lane * 8;
            float e2v[8], e1v[8], pv[8];
            *(float4*)&e2v[0] = *(const float4*)(ex2 + rb);
            *(float4*)&e2v[4] = *(const float4*)(ex2 + rb + 4);
            *(float4*)&e1v[0] = *(const float4*)(ex1 + rb);
            *(float4*)&e1v[4] = *(const float4*)(ex1 + rb + 4);
            *(float4*)&pv[0]  = *(const float4*)(protos + rb);
            *(float4*)&pv[4]  = *(const float4*)(protos + rb + 4);
            const float N = (float)cls_num[c];

            float v[8], mn = FLT_MAX;
            #pragma unroll
            for (int k = 0; k < 8; k++) {
                v[k] = FAST_SQRT(N * e2v[k] * e2v[k] - e1v[k] * e1v[k]);
                mn = fminf(mn, v[k]);
            }
            #pragma unroll
            for (int off = 1; off < 64; off <<= 1) mn = fminf(mn, __shfl_xor(mn, off));

            float ev[8], s = 0.f, te = 0.f;
            #pragma unroll
            for (int k = 0; k < 8; k++) {
                ev[k] = FAST_EXP2((mn - v[k]) * LOG2E);
                s += ev[k];
                te = fmaf(ev[k] * pv[k], pv[k], te);
            }
            #pragma unroll
            for (int off = 1; off < 64; off <<= 1) {
                s  += __shfl_xor(s, off);
                te += __shfl_xor(te, off);
            }
            const float inv = 1.0f / s;
            if (lane == 0) t3s[lc] = te * inv;

            f16x8 h1, l1, h2, l2;
            #pragma unroll
            for (int k = 0; k < 8; k++) {
                const float rdv = ev[k] * inv;
                const float w2  = -2.0f * rdv * pv[k];
                _Float16 hh, ll;
                split2(rdv, hh, ll); h1[k] = hh; l1[k] = ll;
                split2(w2,  hh, ll); h2[k] = hh; l2[k] = ll;
            }
            const int d = lane * 8;       // feature base 0..504
            *(f16x8*)&BSh[lc][d]         = h1;
            *(f16x8*)&BSh[lc][D_SZ + d]  = h2;
            *(f16x8*)&BSl[lc][d]         = l1;
            *(f16x8*)&BSl[lc][D_SZ + d]  = l2;
        } else {
            // pad class: zero the B row so MFMA contributions vanish
            f16x8 z;
            #pragma unroll
            for (int k = 0; k < 8; k++) z[k] = (_Float16)0.f;
            const int d = lane * 8;
            *(f16x8*)&BSh[lc][d]        = z;
            *(f16x8*)&BSh[lc][D_SZ + d] = z;
            *(f16x8*)&BSl[lc][d]        = z;
            *(f16x8*)&BSl[lc][D_SZ + d] = z;
        }
    }
    __syncthreads();                      // B tile + t3s complete

    // ---- Phase B: full-K GEMM, BK=64, reg-prefetched staging ---------------
    const int mw = w * 16;                // wave tile origin in b (0..112)
    const int lr = lane & 15;
    const int kg = lane >> 4;

    f32x4 acc;
    #pragma unroll
    for (int r = 0; r < 4; r++) acc[r] = 0.f;

    for (int ch = 0; ch < K2 / BK; ch++) {        // 16 chunks
        if (ch + 1 < K2 / BK) load_chunk(ch + 1, nxt);   // prefetch next

        const bool sq = (ch < 8);                 // first half of K2 -> x^2
        float av[16];
        *(float4*)&av[0]  = cur[0];
        *(float4*)&av[4]  = cur[1];
        *(float4*)&av[8]  = cur[2];
        *(float4*)&av[12] = cur[3];
        if (sq) {
            #pragma unroll
            for (int k = 0; k < 16; k++) av[k] *= av[k];
        }
        f16x8 ah0, ah1, al0, al1;
        #pragma unroll
        for (int k = 0; k < 8; k++) {
            _Float16 hh, ll;
            split2(av[k], hh, ll);     ah0[k] = hh; al0[k] = ll;
            split2(av[k + 8], hh, ll); ah1[k] = hh; al1[k] = ll;
        }

        __syncthreads();                  // previous iter's frag reads done
        *(f16x8*)&Ah[srow][scol]     = ah0;
        *(f16x8*)&Ah[srow][scol + 8] = ah1;
        *(f16x8*)&Al[srow][scol]     = al0;
        *(f16x8*)&Al[srow][scol + 8] = al1;
        __syncthreads();                  // A tile visible

        #pragma unroll
        for (int sub = 0; sub < 2; sub++) {
            const int kc = sub * 32 + kg * 8;
            const f16x8 fah = *(const f16x8*)&Ah[mw + lr][kc];
            const f16x8 fal = *(const f16x8*)&Al[mw + lr][kc];
            const f16x8 fbh = *(const f16x8*)&BSh[lr][ch * BK + kc];
            const f16x8 fbl = *(const f16x8*)&BSl[lr][ch * BK + kc];
            acc = __builtin_amdgcn_mfma_f32_16x16x32_f16(fal, fbl, acc, 0, 0, 0);
            acc = __builtin_amdgcn_mfma_f32_16x16x32_f16(fah, fbl, acc, 0, 0, 0);
            acc = __builtin_amdgcn_mfma_f32_16x16x32_f16(fal, fbh, acc, 0, 0, 0);
            acc = __builtin_amdgcn_mfma_f32_16x16x32_f16(fah, fbh, acc, 0, 0, 0);
        }

        if (ch + 1 < K2 / BK) {
            cur[0] = nxt[0]; cur[1] = nxt[1];
            cur[2] = nxt[2]; cur[3] = nxt[3];
        }
    }

    // Epilogue: C/D layout (verified m89/m91): col = lane&15, row = kg*4+reg.
    // simi = acc + t3[c] (t3 folded here so topk needs neither part nor t3).
    const int c = c0 + lr;
    if (c < C_SZ) {
        const float t3v = t3s[lr];
        #pragma unroll
        for (int r = 0; r < 4; r++) {
            const int b = b0 + mw + kg * 4 + r;
            simi[(size_t)b * C_SZ + c] = acc[r] + t3v;
        }
    }
}

// ---------------------------------------------------------------------------
// Top-K: per row (one wave each), 10x butterfly min with index tie-break
// (lower index wins == lax.top_k stability). Reads simi directly.
// out[0..B): predict (float-encoded int), out[B..): topk_conf [B][K]
// ---------------------------------------------------------------------------
__global__ __launch_bounds__(256) void topk_kernel(const float* __restrict__ ws,
                                                   const int* __restrict__ proto_label,
                                                   float* __restrict__ out) {
    const float* simi = ws + SIMI_OFF;
    const int wid = threadIdx.x >> 6;
    const int lane = threadIdx.x & 63;
    const int b = blockIdx.x * 4 + wid;

    float vals[16];
    #pragma unroll
    for (int j = 0; j < 16; j++) {
        const int c = lane + j * 64;
        vals[j] = (c < C_SZ) ? simi[(size_t)b * C_SZ + c] : FLT_MAX;
    }

    float kv[K_TOP];
    int ki[K_TOP];
    for (int t = 0; t < K_TOP; t++) {
        float bv = FLT_MAX;
        int bi = 0x7fffffff;
        #pragma unroll
        for (int j = 0; j < 16; j++) {
            const int c = lane + j * 64;
            if (vals[j] < bv) { bv = vals[j]; bi = c; }
        }
        #pragma unroll
        for (int off = 1; off < 64; off <<= 1) {
            const float ov = __shfl_xor(bv, off);
            const int oi = __shfl_xor(bi, off);
            if (ov < bv || (ov == bv && oi < bi)) { bv = ov; bi = oi; }
        }
        kv[t] = bv;
        ki[t] = bi;
        if ((bi & 63) == lane) vals[bi >> 6] = FLT_MAX;
    }

    if (lane == 0) {
        float S = 0.f;
        #pragma unroll
        for (int t = 0; t < K_TOP; t++) S += kv[t];
        float conf[K_TOP];
        #pragma unroll
        for (int t = 0; t < K_TOP; t++) {
            conf[t] = S / kv[t];
            out[B_SZ + b * K_TOP + t] = conf[t];
        }
        int best = 0;
        for (int t = 1; t < K_TOP; t++)
            if (conf[t] > conf[best]) best = t;
        out[b] = (float)proto_label[ki[best]];
    }
}

extern "C" void kernel_launch(void* const* d_in, const int* in_sizes, int n_in,
                              void* d_out, int out_size, void* d_ws, size_t ws_size,
                              hipStream_t stream) {
    const float* x           = (const float*)d_in[0];
    const float* protos      = (const float*)d_in[1];
    const float* ex2         = (const float*)d_in[2];
    const float* ex1         = (const float*)d_in[3];
    const int*   cls_num     = (const int*)d_in[4];
    const int*   proto_label = (const int*)d_in[5];

    float* ws  = (float*)d_ws;
    float* out = (float*)d_out;

    fused_kernel<<<256, 512, 0, stream>>>(x, protos, ex2, ex1, cls_num,
                                          ws + SIMI_OFF);

    topk_kernel<<<B_SZ / 4, 256, 0, stream>>>(ws, proto_label, out);
}

// Round 10
// 96.346 us; speedup vs baseline: 1.7130x; 1.0025x over previous
//
#include <hip/hip_runtime.h>
#include <math.h>
#include <float.h>

#define B_SZ 512
#define C_SZ 1000
#define D_SZ 512
#define K_TOP 10
#define K2 1024                       // [x^2 | x] vs [rd | -2*rd*p]

// ws layout (floats): simi [B][C] only (2.05 MB)
#define SIMI_OFF 0

// Split-C fused GEMM: each block owns 128 b-rows x 16 classes, FULL K=1024.
// R9 lesson: A-tile LDS staging forced 2 barriers/chunk at 1 block/CU ->
// ~25 us of exposed latency. Fix: A fragments load DIRECTLY from global
// (x is L2-resident; 4 kg-groups cover 128B contiguous per row) -> zero
// K-loop barriers, LDS 100.6->66.1 KB -> 2 blocks/CU, 16 waves/CU.
#define BM 128
#define BN 16
#define BK 64
#define LDB 1032    // B row stride (f16): 2064B rows, 16B-aligned, 2-way alias

using f16x8 = __attribute__((ext_vector_type(8))) _Float16;
using f32x4 = __attribute__((ext_vector_type(4))) float;

#if __has_builtin(__builtin_amdgcn_exp2f)
#define FAST_EXP2(x) __builtin_amdgcn_exp2f(x)
#else
#define FAST_EXP2(x) exp2f(x)
#endif
#if __has_builtin(__builtin_amdgcn_sqrtf)
#define FAST_SQRT(x) __builtin_amdgcn_sqrtf(x)
#else
#define FAST_SQRT(x) sqrtf(x)
#endif
#define LOG2E 1.44269504088896340736f

__device__ __forceinline__ void split2(float v, _Float16& h, _Float16& l) {
    h = (_Float16)v;
    l = (_Float16)(v - (float)h);
}

// ---------------------------------------------------------------------------
// Fused prep+GEMM, split-C, barrier-free K-loop.
// Grid 256 blocks (cx = bid&63 -> same-cx class groups L2-local under %8 XCD
// round-robin), 512 thr (8 waves), 2 blocks/CU (66.1 KB LDS, VGPR<=128).
// Phase A: 16 classes/block (2/wave, 4x total redundancy): full-row softmax
//   with HW transcendentals -> [rd | -2*rd*p] hi/lo f16 in persistent LDS;
//   t3 in LDS (folded into simi at epilogue). ONE barrier after.
// Phase B: full-K split-f16 MFMA GEMM; A-frags straight from global (L2),
//   1-chunk register prefetch; B-frags from read-only LDS. No barriers.
// ---------------------------------------------------------------------------
__global__ __launch_bounds__(512, 4) void fused_kernel(const float* __restrict__ x,
                                                       const float* __restrict__ protos,
                                                       const float* __restrict__ ex2,
                                                       const float* __restrict__ ex1,
                                                       const int* __restrict__ cls_num,
                                                       float* __restrict__ simi) {
    __shared__ __align__(16) _Float16 BSh[BN][LDB];
    __shared__ __align__(16) _Float16 BSl[BN][LDB];
    __shared__ float t3s[BN];

    const int tid  = threadIdx.x;
    const int lane = tid & 63;
    const int w    = tid >> 6;            // 0..7
    const int cx = blockIdx.x & 63;       // low bits -> XCD-local class groups
    const int by = blockIdx.x >> 6;       // 0..3
    const int c0 = cx * BN;
    const int b0 = by * BM;
    if (c0 >= C_SZ) return;               // cx==63 (c0=1008): idle block

    const int mw = w * 16;                // wave tile origin in b
    const int lr = lane & 15;             // A row / C col within fragment
    const int kg = lane >> 4;             // k-group

    // per-lane A row pointer (fragment layout: row=lr, k=kg*8+j)
    const float* xrow = x + (size_t)(b0 + mw + lr) * D_SZ;

    auto load_a = [&](int ch, float4* d) {
        const int kx = (ch < 8 ? ch * BK : ch * BK - D_SZ) + kg * 8;
        const float* xp = xrow + kx;
        d[0] = *(const float4*)(xp);          // sub0: k = kx .. +7
        d[1] = *(const float4*)(xp + 4);
        d[2] = *(const float4*)(xp + 32);     // sub1: k = kx+32 .. +39
        d[3] = *(const float4*)(xp + 36);
    };

    float4 cur[4], nxt[4];
    load_a(0, cur);                       // in flight during all of Phase A

    // ---- Phase A: 2 class rows per wave ------------------------------------
    #pragma unroll
    for (int r = 0; r < 2; r++) {
        const int lc = w * 2 + r;         // 0..15
        const int c  = c0 + lc;
        if (c < C_SZ) {
            const size_t rb = (size_t)c * D_SZ + lane * 8;
            float e2v[8], e1v[8], pv[8];
            *(float4*)&e2v[0] = *(const float4*)(ex2 + rb);
            *(float4*)&e2v[4] = *(const float4*)(ex2 + rb + 4);
            *(float4*)&e1v[0] = *(const float4*)(ex1 + rb);
            *(float4*)&e1v[4] = *(const float4*)(ex1 + rb + 4);
            *(float4*)&pv[0]  = *(const float4*)(protos + rb);
            *(float4*)&pv[4]  = *(const float4*)(protos + rb + 4);
            const float N = (float)cls_num[c];

            float v[8], mn = FLT_MAX;
            #pragma unroll
            for (int k = 0; k < 8; k++) {
                v[k] = FAST_SQRT(N * e2v[k] * e2v[k] - e1v[k] * e1v[k]);
                mn = fminf(mn, v[k]);
            }
            #pragma unroll
            for (int off = 1; off < 64; off <<= 1) mn = fminf(mn, __shfl_xor(mn, off));

            float ev[8], s = 0.f, te = 0.f;
            #pragma unroll
            for (int k = 0; k < 8; k++) {
                ev[k] = FAST_EXP2((mn - v[k]) * LOG2E);
                s += ev[k];
                te = fmaf(ev[k] * pv[k], pv[k], te);
            }
            #pragma unroll
            for (int off = 1; off < 64; off <<= 1) {
                s  += __shfl_xor(s, off);
                te += __shfl_xor(te, off);
            }
            const float inv = 1.0f / s;
            if (lane == 0) t3s[lc] = te * inv;

            f16x8 h1, l1, h2, l2;
            #pragma unroll
            for (int k = 0; k < 8; k++) {
                const float rdv = ev[k] * inv;
                const float w2  = -2.0f * rdv * pv[k];
                _Float16 hh, ll;
                split2(rdv, hh, ll); h1[k] = hh; l1[k] = ll;
                split2(w2,  hh, ll); h2[k] = hh; l2[k] = ll;
            }
            const int d = lane * 8;       // feature base 0..504
            *(f16x8*)&BSh[lc][d]         = h1;
            *(f16x8*)&BSh[lc][D_SZ + d]  = h2;
            *(f16x8*)&BSl[lc][d]         = l1;
            *(f16x8*)&BSl[lc][D_SZ + d]  = l2;
        } else {
            // pad class: zero the B row so MFMA contributions vanish
            f16x8 z;
            #pragma unroll
            for (int k = 0; k < 8; k++) z[k] = (_Float16)0.f;
            const int d = lane * 8;
            *(f16x8*)&BSh[lc][d]        = z;
            *(f16x8*)&BSh[lc][D_SZ + d] = z;
            *(f16x8*)&BSl[lc][d]        = z;
            *(f16x8*)&BSl[lc][D_SZ + d] = z;
        }
    }
    __syncthreads();                      // B tile + t3s complete (only barrier)

    // ---- Phase B: full-K GEMM, no barriers, A from global ------------------
    f32x4 acc;
    #pragma unroll
    for (int r = 0; r < 4; r++) acc[r] = 0.f;

    for (int ch = 0; ch < K2 / BK; ch++) {        // 16 chunks
        if (ch + 1 < K2 / BK) load_a(ch + 1, nxt);

        float av[16];
        *(float4*)&av[0]  = cur[0];
        *(float4*)&av[4]  = cur[1];
        *(float4*)&av[8]  = cur[2];
        *(float4*)&av[12] = cur[3];
        if (ch < 8) {                     // x^2 half of K2
            #pragma unroll
            for (int k = 0; k < 16; k++) av[k] *= av[k];
        }
        f16x8 ah0, al0, ah1, al1;
        #pragma unroll
        for (int k = 0; k < 8; k++) {
            _Float16 hh, ll;
            split2(av[k], hh, ll);     ah0[k] = hh; al0[k] = ll;
            split2(av[k + 8], hh, ll); ah1[k] = hh; al1[k] = ll;
        }

        const int kb = ch * BK + kg * 8;
        {
            const f16x8 fbh = *(const f16x8*)&BSh[lr][kb];
            const f16x8 fbl = *(const f16x8*)&BSl[lr][kb];
            acc = __builtin_amdgcn_mfma_f32_16x16x32_f16(al0, fbl, acc, 0, 0, 0);
            acc = __builtin_amdgcn_mfma_f32_16x16x32_f16(ah0, fbl, acc, 0, 0, 0);
            acc = __builtin_amdgcn_mfma_f32_16x16x32_f16(al0, fbh, acc, 0, 0, 0);
            acc = __builtin_amdgcn_mfma_f32_16x16x32_f16(ah0, fbh, acc, 0, 0, 0);
        }
        {
            const f16x8 fbh = *(const f16x8*)&BSh[lr][kb + 32];
            const f16x8 fbl = *(const f16x8*)&BSl[lr][kb + 32];
            acc = __builtin_amdgcn_mfma_f32_16x16x32_f16(al1, fbl, acc, 0, 0, 0);
            acc = __builtin_amdgcn_mfma_f32_16x16x32_f16(ah1, fbl, acc, 0, 0, 0);
            acc = __builtin_amdgcn_mfma_f32_16x16x32_f16(al1, fbh, acc, 0, 0, 0);
            acc = __builtin_amdgcn_mfma_f32_16x16x32_f16(ah1, fbh, acc, 0, 0, 0);
        }

        if (ch + 1 < K2 / BK) {
            cur[0] = nxt[0]; cur[1] = nxt[1];
            cur[2] = nxt[2]; cur[3] = nxt[3];
        }
    }

    // Epilogue: C/D layout (verified m89/m91): col = lane&15, row = kg*4+reg.
    // simi = acc + t3[c] (t3 folded here so topk needs neither part nor t3).
    const int c = c0 + lr;
    if (c < C_SZ) {
        const float t3v = t3s[lr];
        #pragma unroll
        for (int r = 0; r < 4; r++) {
            const int b = b0 + mw + kg * 4 + r;
            simi[(size_t)b * C_SZ + c] = acc[r] + t3v;
        }
    }
}

// ---------------------------------------------------------------------------
// Top-K: per row (one wave each), 10x butterfly min with index tie-break
// (lower index wins == lax.top_k stability). Reads simi directly.
// out[0..B): predict (float-encoded int), out[B..): topk_conf [B][K]
// ---------------------------------------------------------------------------
__global__ __launch_bounds__(256) void topk_kernel(const float* __restrict__ ws,
                                                   const int* __restrict__ proto_label,
                                                   float* __restrict__ out) {
    const float* simi = ws + SIMI_OFF;
    const int wid = threadIdx.x >> 6;
    const int lane = threadIdx.x & 63;
    const int b = blockIdx.x * 4 + wid;

    float vals[16];
    #pragma unroll
    for (int j = 0; j < 16; j++) {
        const int c = lane + j * 64;
        vals[j] = (c < C_SZ) ? simi[(size_t)b * C_SZ + c] : FLT_MAX;
    }

    float kv[K_TOP];
    int ki[K_TOP];
    for (int t = 0; t < K_TOP; t++) {
        float bv = FLT_MAX;
        int bi = 0x7fffffff;
        #pragma unroll
        for (int j = 0; j < 16; j++) {
            const int c = lane + j * 64;
            if (vals[j] < bv) { bv = vals[j]; bi = c; }
        }
        #pragma unroll
        for (int off = 1; off < 64; off <<= 1) {
            const float ov = __shfl_xor(bv, off);
            const int oi = __shfl_xor(bi, off);
            if (ov < bv || (ov == bv && oi < bi)) { bv = ov; bi = oi; }
        }
        kv[t] = bv;
        ki[t] = bi;
        if ((bi & 63) == lane) vals[bi >> 6] = FLT_MAX;
    }

    if (lane == 0) {
        float S = 0.f;
        #pragma unroll
        for (int t = 0; t < K_TOP; t++) S += kv[t];
        float conf[K_TOP];
        #pragma unroll
        for (int t = 0; t < K_TOP; t++) {
            conf[t] = S / kv[t];
            out[B_SZ + b * K_TOP + t] = conf[t];
        }
        int best = 0;
        for (int t = 1; t < K_TOP; t++)
            if (conf[t] > conf[best]) best = t;
        out[b] = (float)proto_label[ki[best]];
    }
}

extern "C" void kernel_launch(void* const* d_in, const int* in_sizes, int n_in,
                              void* d_out, int out_size, void* d_ws, size_t ws_size,
                              hipStream_t stream) {
    const float* x           = (const float*)d_in[0];
    const float* protos      = (const float*)d_in[1];
    const float* ex2         = (const float*)d_in[2];
    const float* ex1         = (const float*)d_in[3];
    const int*   cls_num     = (const int*)d_in[4];
    const int*   proto_label = (const int*)d_in[5];

    float* ws  = (float*)d_ws;
    float* out = (float*)d_out;

    fused_kernel<<<256, 512, 0, stream>>>(x, protos, ex2, ex1, cls_num,
                                          ws + SIMI_OFF);

    topk_kernel<<<B_SZ / 4, 256, 0, stream>>>(ws, proto_label, out);
}